// Round 2
// baseline (1994.919 us; speedup 1.0000x reference)
//
#include <hip/hip_runtime.h>
#include <hip/hip_fp16.h>

// All tensors fp32 in global (per reference). Intermediates stored fp16.
// d_ws usage: exactly 128 MiB (wsA 64Mi + wsB 64Mi).
// d_in[1] (mask m, unused by the math) = 2 MB fp32 scratch:
//   [0, 262144)          sc   : scores [bh][qi][ki] fp32 (zeroed, atomicAdd)
//   [262144, 372736)     wT   : 3 conv weights transposed [(c*9+tap)*64 + o]
// d_out (128 MiB fp32 out) doubles as scratch early:
//   halfs [0, 33554432)  v    ; halfs [33554432, 67108864)  y
#define SCALE 0.011048543456039806f   // 1/sqrt(8192)

__device__ inline float ldval(const float* p, int i)  { return p[i]; }
__device__ inline float ldval(const __half* p, int i) { return __half2float(p[i]); }
__device__ inline void  stval(float* p, int i, float v)  { p[i] = v; }
__device__ inline void  stval(__half* p, int i, float v) { p[i] = __float2half(v); }

// ---------------- prep: zero score buffer + transpose conv weights ----------------
__global__ __launch_bounds__(256) void prep_kernel(const float* __restrict__ wo,
                                                   const float* __restrict__ wf1,
                                                   const float* __restrict__ wf2,
                                                   float* __restrict__ scr) {
    int i = blockIdx.x * 256 + threadIdx.x;   // grid 1456 -> 372736 exact
    if (i < 262144) {
        scr[i] = 0.f;
    } else {
        int j = i - 262144;                   // < 110592
        int mtx = j / 36864;
        int r = j % 36864;                    // = (c*9+tap)*64 + o
        int o = r & 63, ct = r >> 6;
        int c = ct / 9, tap = ct - c * 9;
        const float* src = (mtx == 0) ? wo : ((mtx == 1) ? wf1 : wf2);
        scr[262144 + j] = src[(o * 64 + c) * 9 + tap];
    }
}

// ---------------- QKV 1x1 conv: thread=pixel, x in regs, weights via s_load ----------------
__global__ __launch_bounds__(256) void qkv_kernel(const float* __restrict__ x,
                                                  const float* __restrict__ wq, const float* __restrict__ bq,
                                                  const float* __restrict__ wk, const float* __restrict__ bk,
                                                  const float* __restrict__ wv, const float* __restrict__ bv,
                                                  __half* __restrict__ q, __half* __restrict__ k,
                                                  __half* __restrict__ v) {
    int pix = blockIdx.x * 256 + threadIdx.x;   // b*65536 + hw
    int b = pix >> 16;
    int hw = pix & 65535;
    int base = (b << 22) + hw;
    float xr[64];
    #pragma unroll
    for (int c = 0; c < 64; c++) xr[c] = x[base + (c << 16)];

    for (int m = 0; m < 3; m++) {
        const float* wm = (m == 0) ? wq : ((m == 1) ? wk : wv);
        const float* bm = (m == 0) ? bq : ((m == 1) ? bk : bv);
        __half* out = (m == 0) ? q : ((m == 1) ? k : v);
        for (int o = 0; o < 64; o++) {
            float acc = bm[o];
            #pragma unroll
            for (int c = 0; c < 64; c++) acc += xr[c] * wm[o * 64 + c];
            out[base + (o << 16)] = __float2half(acc);
        }
    }
}

// ---------------- scores partials: block=(dk chunk ec, bh); atomicAdd into sc ----------------
__global__ __launch_bounds__(256) void scores_kernel(const __half* __restrict__ q,
                                                     const __half* __restrict__ k,
                                                     float* __restrict__ sc) {
    __shared__ float Qs[64][68];   // [e_local][window], stride 68 keeps float4 16B-aligned
    __shared__ float Ks[64][68];
    int ec = blockIdx.x;           // dk 0..7
    int bh = blockIdx.y;           // 0..63
    int b = bh >> 3, h = bh & 7;
    int cbase = ((b * 64 + h * 8 + ec) << 16);
    int t = threadIdx.x;
    int qg = t >> 4, kg = t & 15;
    float acc[4][4] = {};

    for (int j = 0; j < 16; j++) {           // 16 sub-tiles of 64 e
        __syncthreads();
        #pragma unroll
        for (int i = 0; i < 16; i++) {
            int idx = i * 256 + t;
            int wi = idx >> 6;
            int el = idx & 63;
            int eg = j * 64 + el;            // e within this dk's 1024
            int py = eg >> 5, px = eg & 31;
            int oy = wi >> 3, ox = wi & 7;
            int a = cbase + ((oy * 32 + py) << 8) + ox * 32 + px;
            Qs[el][wi] = __half2float(q[a]);
            Ks[el][wi] = __half2float(k[a]);
        }
        __syncthreads();
        for (int e = 0; e < 64; e++) {
            float4 qv = *(const float4*)&Qs[e][qg * 4];
            float4 kv = *(const float4*)&Ks[e][kg * 4];
            float qa[4] = {qv.x, qv.y, qv.z, qv.w};
            float ka[4] = {kv.x, kv.y, kv.z, kv.w};
            #pragma unroll
            for (int i = 0; i < 4; i++)
                #pragma unroll
                for (int jj = 0; jj < 4; jj++)
                    acc[i][jj] += qa[i] * ka[jj];
        }
    }
    float* dst = sc + bh * 4096;
    #pragma unroll
    for (int i = 0; i < 4; i++)
        #pragma unroll
        for (int jj = 0; jj < 4; jj++)
            atomicAdd(&dst[(qg * 4 + i) * 64 + kg * 4 + jj], acc[i][jj]);
}

// ---------------- softmax in place on sc: block = one row, 64 lanes = ki ----------------
__global__ __launch_bounds__(64) void softmax_kernel(float* __restrict__ sc) {
    int row = blockIdx.x;           // bh*64 + qi
    int ki = threadIdx.x;
    float s = sc[row * 64 + ki] * SCALE;
    float m = s;
    #pragma unroll
    for (int off = 32; off; off >>= 1) m = fmaxf(m, __shfl_xor(m, off));
    float e = __expf(s - m);
    float sum = e;
    #pragma unroll
    for (int off = 32; off; off >>= 1) sum += __shfl_xor(sum, off);
    sc[row * 64 + ki] = e / sum;    // safe: each lane touches only its own element
}

// ---------------- y = P @ V, un-windowed to BCHW fp16 ----------------
__global__ __launch_bounds__(256) void attnout_kernel(const float* __restrict__ p,
                                                      const __half* __restrict__ v,
                                                      __half* __restrict__ y) {
    __shared__ float Ps[64][65];    // [qi][ki]
    __shared__ float Vs[64][132];   // [ki][el]
    int dk = blockIdx.x, bh = blockIdx.y;
    int b = bh >> 3, h = bh & 7;
    int cbase = ((b * 64 + h * 8 + dk) << 16);
    int t = threadIdx.x;
    #pragma unroll
    for (int i = 0; i < 16; i++) {
        int idx = i * 256 + t;
        Ps[idx >> 6][idx & 63] = p[bh * 4096 + idx];
    }
    int qg = t >> 4, eg = t & 15;
    for (int sub = 0; sub < 8; sub++) {      // 8 el-subtiles of 128
        __syncthreads();
        #pragma unroll
        for (int i = 0; i < 32; i++) {
            int idx = i * 256 + t;
            int ki = idx >> 7, el = idx & 127;
            int elg = sub * 128 + el;
            int py = elg >> 5, px = elg & 31;
            int oy = ki >> 3, ox = ki & 7;
            Vs[ki][el] = __half2float(v[cbase + ((oy * 32 + py) << 8) + ox * 32 + px]);
        }
        __syncthreads();
        float acc[4][8] = {};
        for (int ki = 0; ki < 64; ki++) {
            float4 v0 = *(const float4*)&Vs[ki][eg * 8];
            float4 v1 = *(const float4*)&Vs[ki][eg * 8 + 4];
            #pragma unroll
            for (int i = 0; i < 4; i++) {
                float pv = Ps[qg * 4 + i][ki];
                acc[i][0] += pv * v0.x; acc[i][1] += pv * v0.y;
                acc[i][2] += pv * v0.z; acc[i][3] += pv * v0.w;
                acc[i][4] += pv * v1.x; acc[i][5] += pv * v1.y;
                acc[i][6] += pv * v1.z; acc[i][7] += pv * v1.w;
            }
        }
        int elg0 = sub * 128 + eg * 8;
        int py = elg0 >> 5, px = elg0 & 31;
        #pragma unroll
        for (int i = 0; i < 4; i++) {
            int wi = qg * 4 + i;
            int oy = wi >> 3, ox = wi & 7;
            int a = cbase + ((oy * 32 + py) << 8) + ox * 32 + px;
            #pragma unroll
            for (int jj = 0; jj < 8; jj++)
                y[a + jj] = __float2half(acc[i][jj]);
        }
    }
}

// ---------------- direct 3x3 conv, reflect pad, lrelu, optional residual ----------------
// 16 output channels per block (chunk); weights via uniform s_load from wT.
template <typename TRES, typename TOUT>
__global__ __launch_bounds__(256) void conv3x3_kernel(const __half* __restrict__ in,
                                                      const float* __restrict__ wT,
                                                      const float* __restrict__ bias,
                                                      const TRES* __restrict__ res,
                                                      TOUT* __restrict__ out,
                                                      int dil) {
    int chunk = blockIdx.x & 3;
    int y = (blockIdx.x >> 2) & 255;
    int b = blockIdx.x >> 10;
    int t = threadIdx.x;            // x
    int offs[9];
    #pragma unroll
    for (int ky = 0; ky < 3; ky++) {
        int ry = y + (ky - 1) * dil;
        if (ry < 0) ry = -ry;
        if (ry > 255) ry = 510 - ry;
        #pragma unroll
        for (int kx = 0; kx < 3; kx++) {
            int rx = t + (kx - 1) * dil;
            if (rx < 0) rx = -rx;
            if (rx > 255) rx = 510 - rx;
            offs[ky * 3 + kx] = (ry << 8) + rx;
        }
    }
    float acc[16];
    #pragma unroll
    for (int o = 0; o < 16; o++) acc[o] = bias[chunk * 16 + o];
    int bbase = b << 22;
    for (int c = 0; c < 64; c++) {
        const __half* pc = in + bbase + (c << 16);
        float vt[9];
        #pragma unroll
        for (int tap = 0; tap < 9; tap++) vt[tap] = __half2float(pc[offs[tap]]);
        #pragma unroll
        for (int tap = 0; tap < 9; tap++) {
            const float* wr = wT + (c * 9 + tap) * 64 + chunk * 16;
            #pragma unroll
            for (int o = 0; o < 16; o++) acc[o] += vt[tap] * wr[o];
        }
    }
    int obase = bbase + (y << 8) + t;
    #pragma unroll
    for (int o = 0; o < 16; o++) {
        float z = acc[o];
        z = (z > 0.f) ? z : 0.2f * z;
        if (res) z += ldval(res, obase + ((chunk * 16 + o) << 16));
        stval(out, obase + ((chunk * 16 + o) << 16), z);
    }
}

extern "C" void kernel_launch(void* const* d_in, const int* in_sizes, int n_in,
                              void* d_out, int out_size, void* d_ws, size_t ws_size,
                              hipStream_t stream) {
    const float* x   = (const float*)d_in[0];
    float*       scr = (float*)d_in[1];        // mask: unused by math -> scratch
    const float* wq  = (const float*)d_in[2];
    const float* bq  = (const float*)d_in[3];
    const float* wk  = (const float*)d_in[4];
    const float* bk  = (const float*)d_in[5];
    const float* wv  = (const float*)d_in[6];
    const float* bv  = (const float*)d_in[7];
    const float* wo  = (const float*)d_in[8];
    const float* bo  = (const float*)d_in[9];
    const float* wf1 = (const float*)d_in[10];
    const float* bf1 = (const float*)d_in[11];
    const float* wf2 = (const float*)d_in[12];
    const float* bf2 = (const float*)d_in[13];

    __half* wsA = (__half*)d_ws;                               // q, then x1
    __half* wsB = (__half*)((char*)d_ws + 67108864);           // k, then ff1
    __half* vbuf = (__half*)d_out;                             // v (first half of d_out)
    __half* ybuf = vbuf + 33554432;                            // y (second half)
    float*  outf = (float*)d_out;
    float*  sc  = scr;                                         // 262144 floats
    const float* wTo = scr + 262144;
    const float* wT1 = scr + 262144 + 36864;
    const float* wT2 = scr + 262144 + 73728;

    prep_kernel<<<1456, 256, 0, stream>>>(wo, wf1, wf2, scr);
    qkv_kernel<<<2048, 256, 0, stream>>>(x, wq, bq, wk, bk, wv, bv, wsA, wsB, vbuf);
    scores_kernel<<<dim3(8, 64), 256, 0, stream>>>(wsA, wsB, sc);
    softmax_kernel<<<4096, 64, 0, stream>>>(sc);
    attnout_kernel<<<dim3(8, 64), 256, 0, stream>>>(sc, vbuf, ybuf);
    // x1 = x + lrelu(conv_o(y))        -> wsA (fp16)
    conv3x3_kernel<float, __half><<<8192, 256, 0, stream>>>(ybuf, wTo, bo, x, wsA, 1);
    // ff1 = lrelu(conv_f1(x1, dil=2))  -> wsB (fp16)
    conv3x3_kernel<float, __half><<<8192, 256, 0, stream>>>(wsA, wT1, bf1, (const float*)nullptr, wsB, 2);
    // out = x1 + lrelu(conv_f2(ff1))   -> d_out (fp32)
    conv3x3_kernel<__half, float><<<8192, 256, 0, stream>>>(wsB, wT2, bf2, wsA, outf, 1);
}

// Round 3
// 977.163 us; speedup vs baseline: 2.0415x; 2.0415x over previous
//
#include <hip/hip_runtime.h>
#include <hip/hip_fp16.h>

// All global tensors fp32 (per reference). Intermediates fp16.
// d_ws: wsA [0,64Mi) = q then x1 ; wsB [64Mi,128Mi) = k then ff1  (halfs)
// d_out doubles as scratch: halfs [0,33554432) = v ; [33554432,67108864) = y
// d_in[1] (mask, mathematically unused) = 2MB scratch:
//   floats [0,262144)  sc: scores [bh][qi][ki] (zeroed, atomicAdd)
//   halfs after that:  wqkv16 [192][64] ; conv wT16 [3][9][64][64] (tap-major)
#define SCALE 0.011048543456039806f   // 1/sqrt(8192)

typedef _Float16 half8 __attribute__((ext_vector_type(8)));
typedef float f32x4 __attribute__((ext_vector_type(4)));
typedef unsigned int uint32;

__device__ inline float ldval(const float* p, int i)  { return p[i]; }
__device__ inline float ldval(const __half* p, int i) { return __half2float(p[i]); }
__device__ inline void  stval(float* p, int i, float v)  { p[i] = v; }
__device__ inline void  stval(__half* p, int i, float v) { p[i] = __float2half(v); }

// ---------------- prep: zero score buffer + fp16 weight repack ----------------
__global__ __launch_bounds__(256) void prep_kernel(const float* __restrict__ wq,
                                                   const float* __restrict__ wk,
                                                   const float* __restrict__ wv,
                                                   const float* __restrict__ wo,
                                                   const float* __restrict__ wf1,
                                                   const float* __restrict__ wf2,
                                                   float* __restrict__ scr) {
    int i = blockIdx.x * 256 + threadIdx.x;   // grid 1504 -> 385024 exact
    if (i < 262144) { scr[i] = 0.f; return; }
    __half* wh = (__half*)(scr + 262144);
    int j = i - 262144;
    if (j < 12288) {                           // qkv: wh[gm*64+c], gm=0..191
        int gm = j >> 6, c = j & 63;
        int mtx = gm >> 6, o = gm & 63;
        const float* src = (mtx == 0) ? wq : ((mtx == 1) ? wk : wv);
        wh[j] = __float2half(src[o * 64 + c]);
    } else {                                   // conv: [mtx][tap][o*64+c]
        int r = j - 12288;                     // < 110592
        int mtx = r / 36864;
        int q2 = r - mtx * 36864;
        int tap = q2 >> 12;
        int oc = q2 & 4095;
        int o = oc >> 6, c = oc & 63;
        const float* src = (mtx == 0) ? wo : ((mtx == 1) ? wf1 : wf2);
        wh[j] = __float2half(src[(o * 64 + c) * 9 + tap]);
    }
}

// ---------------- QKV: one M=192,K=64 MFMA GEMM over 256-pixel row tiles ----------------
__global__ __launch_bounds__(512) void qkv_mfma(const float* __restrict__ x,
                                                const __half* __restrict__ wqkv,
                                                const float* __restrict__ bq,
                                                const float* __restrict__ bk,
                                                const float* __restrict__ bv,
                                                __half* __restrict__ q,
                                                __half* __restrict__ k,
                                                __half* __restrict__ v) {
    __shared__ __align__(16) __half Xs[256 * 72];   // [pix][c], stride 72
    __shared__ __align__(16) __half Ws[192 * 72];   // [o192][c]
    int t = threadIdx.x;
    int bx = blockIdx.x;                 // b*256 + row
    int b = bx >> 8, row = bx & 255;
    int hw0 = row << 8;
    int bbase = b << 22;

    for (int i = 0; i < 32; i++) {       // 16384 x-elems fp32->fp16
        int idx = i * 512 + t;
        int c = idx >> 8, p = idx & 255;
        Xs[p * 72 + c] = __float2half(x[bbase + (c << 16) + hw0 + p]);
    }
    const uint32* src = (const uint32*)wqkv;   // 6144 uints
    #pragma unroll
    for (int i = 0; i < 12; i++) {
        int idx = i * 512 + t;
        int o = idx >> 5, c2 = idx & 31;
        *(uint32*)&Ws[o * 72 + c2 * 2] = src[idx];
    }
    __syncthreads();

    int wave = t >> 6, lane = t & 63;
    int l15 = lane & 15, quad = lane >> 4;
    int mg = wave >> 2, ng = wave & 3;   // m-half (6 tiles), n-quarter (4 tiles)
    f32x4 acc[4][6];
    #pragma unroll
    for (int i = 0; i < 4; i++)
        #pragma unroll
        for (int m = 0; m < 6; m++) acc[i][m] = (f32x4){0.f, 0.f, 0.f, 0.f};

    #pragma unroll
    for (int kc = 0; kc < 2; kc++) {
        half8 af[6];
        #pragma unroll
        for (int m = 0; m < 6; m++)
            af[m] = *(const half8*)&Ws[((mg * 6 + m) * 16 + l15) * 72 + kc * 32 + quad * 8];
        #pragma unroll
        for (int i = 0; i < 4; i++) {
            half8 bf = *(const half8*)&Xs[(ng * 64 + i * 16 + l15) * 72 + kc * 32 + quad * 8];
            #pragma unroll
            for (int m = 0; m < 6; m++)
                acc[i][m] = __builtin_amdgcn_mfma_f32_16x16x32_f16(af[m], bf, acc[i][m], 0, 0, 0);
        }
    }
    #pragma unroll
    for (int i = 0; i < 4; i++) {
        int pix = hw0 + ng * 64 + i * 16 + l15;
        #pragma unroll
        for (int m = 0; m < 6; m++) {
            int gm = mg * 6 + m;            // 0..11
            int mtx = gm >> 2;
            int ob = (gm & 3) * 16 + quad * 4;
            __half* dst = (mtx == 0) ? q : ((mtx == 1) ? k : v);
            const float* bb = (mtx == 0) ? bq : ((mtx == 1) ? bk : bv);
            #pragma unroll
            for (int r = 0; r < 4; r++) {
                float z = acc[i][m][r] + bb[ob + r];
                dst[bbase + ((ob + r) << 16) + pix] = __float2half(z);
            }
        }
    }
}

// ---------------- scores partials (unchanged from R2) ----------------
__global__ __launch_bounds__(256) void scores_kernel(const __half* __restrict__ q,
                                                     const __half* __restrict__ k,
                                                     float* __restrict__ sc) {
    __shared__ float Qs[64][68];
    __shared__ float Ks[64][68];
    int ec = blockIdx.x;
    int bh = blockIdx.y;
    int b = bh >> 3, h = bh & 7;
    int cbase = ((b * 64 + h * 8 + ec) << 16);
    int t = threadIdx.x;
    int qg = t >> 4, kg = t & 15;
    float acc[4][4] = {};
    for (int j = 0; j < 16; j++) {
        __syncthreads();
        #pragma unroll
        for (int i = 0; i < 16; i++) {
            int idx = i * 256 + t;
            int wi = idx >> 6;
            int el = idx & 63;
            int eg = j * 64 + el;
            int py = eg >> 5, px = eg & 31;
            int oy = wi >> 3, ox = wi & 7;
            int a = cbase + ((oy * 32 + py) << 8) + ox * 32 + px;
            Qs[el][wi] = __half2float(q[a]);
            Ks[el][wi] = __half2float(k[a]);
        }
        __syncthreads();
        for (int e = 0; e < 64; e++) {
            float4 qv = *(const float4*)&Qs[e][qg * 4];
            float4 kv = *(const float4*)&Ks[e][kg * 4];
            float qa[4] = {qv.x, qv.y, qv.z, qv.w};
            float ka[4] = {kv.x, kv.y, kv.z, kv.w};
            #pragma unroll
            for (int i = 0; i < 4; i++)
                #pragma unroll
                for (int jj = 0; jj < 4; jj++)
                    acc[i][jj] += qa[i] * ka[jj];
        }
    }
    float* dst = sc + bh * 4096;
    #pragma unroll
    for (int i = 0; i < 4; i++)
        #pragma unroll
        for (int jj = 0; jj < 4; jj++)
            atomicAdd(&dst[(qg * 4 + i) * 64 + kg * 4 + jj], acc[i][jj]);
}

// ---------------- softmax (unchanged) ----------------
__global__ __launch_bounds__(64) void softmax_kernel(float* __restrict__ sc) {
    int row = blockIdx.x;
    int ki = threadIdx.x;
    float s = sc[row * 64 + ki] * SCALE;
    float m = s;
    #pragma unroll
    for (int off = 32; off; off >>= 1) m = fmaxf(m, __shfl_xor(m, off));
    float e = __expf(s - m);
    float sum = e;
    #pragma unroll
    for (int off = 32; off; off >>= 1) sum += __shfl_xor(sum, off);
    sc[row * 64 + ki] = e / sum;
}

// ---------------- y = P @ V (unchanged) ----------------
__global__ __launch_bounds__(256) void attnout_kernel(const float* __restrict__ p,
                                                      const __half* __restrict__ v,
                                                      __half* __restrict__ y) {
    __shared__ float Ps[64][65];
    __shared__ float Vs[64][132];
    int dk = blockIdx.x, bh = blockIdx.y;
    int b = bh >> 3, h = bh & 7;
    int cbase = ((b * 64 + h * 8 + dk) << 16);
    int t = threadIdx.x;
    #pragma unroll
    for (int i = 0; i < 16; i++) {
        int idx = i * 256 + t;
        Ps[idx >> 6][idx & 63] = p[bh * 4096 + idx];
    }
    int qg = t >> 4, eg = t & 15;
    for (int sub = 0; sub < 8; sub++) {
        __syncthreads();
        #pragma unroll
        for (int i = 0; i < 32; i++) {
            int idx = i * 256 + t;
            int ki = idx >> 7, el = idx & 127;
            int elg = sub * 128 + el;
            int py = elg >> 5, px = elg & 31;
            int oy = ki >> 3, ox = ki & 7;
            Vs[ki][el] = __half2float(v[cbase + ((oy * 32 + py) << 8) + ox * 32 + px]);
        }
        __syncthreads();
        float acc[4][8] = {};
        for (int ki = 0; ki < 64; ki++) {
            float4 v0 = *(const float4*)&Vs[ki][eg * 8];
            float4 v1 = *(const float4*)&Vs[ki][eg * 8 + 4];
            #pragma unroll
            for (int i = 0; i < 4; i++) {
                float pv = Ps[qg * 4 + i][ki];
                acc[i][0] += pv * v0.x; acc[i][1] += pv * v0.y;
                acc[i][2] += pv * v0.z; acc[i][3] += pv * v0.w;
                acc[i][4] += pv * v1.x; acc[i][5] += pv * v1.y;
                acc[i][6] += pv * v1.z; acc[i][7] += pv * v1.w;
            }
        }
        int elg0 = sub * 128 + eg * 8;
        int py = elg0 >> 5, px = elg0 & 31;
        #pragma unroll
        for (int i = 0; i < 4; i++) {
            int wi = qg * 4 + i;
            int oy = wi >> 3, ox = wi & 7;
            int a = cbase + ((oy * 32 + py) << 8) + ox * 32 + px;
            #pragma unroll
            for (int jj = 0; jj < 8; jj++)
                y[a + jj] = __float2half(acc[i][jj]);
        }
    }
}

// ---------------- conv3x3 via MFMA implicit GEMM ----------------
// Tile 8x32 outputs/block, 4 waves; input tile transposed in LDS [pix][c] (stride 72).
// Per tap: stage W_tap [64][64] in LDS, 2 K-chunks of 32, 16 MFMA / 8 ds_read_b128 per wave.
template <int DIL, typename TRES, typename TOUT>
__global__ __launch_bounds__(256) void conv3x3_mfma(const __half* __restrict__ in,
                                                    const __half* __restrict__ wt,
                                                    const float* __restrict__ bias,
                                                    const TRES* __restrict__ res,
                                                    TOUT* __restrict__ out) {
    constexpr int TH = 8, TW = 32;
    constexpr int PH = TH + 2 * DIL, PW = TW + 2 * DIL;
    constexpr int NP = PH * PW;
    __shared__ __align__(16) __half Xs[NP * 72];
    __shared__ __align__(16) __half Ws[64 * 72];

    int t = threadIdx.x;
    int bx = blockIdx.x;
    int tc = bx & 7, tr = (bx >> 3) & 31, b = bx >> 8;
    int x0 = tc * TW, y0 = tr * TH;
    int bbase = b << 22;

    for (int i = 0; i < NP * 64 / 256; i++) {
        int idx = i * 256 + t;
        int c = idx / NP, p = idx - c * NP;
        int py = p / PW, px = p - py * PW;
        int gy = y0 + py - DIL; gy = gy < 0 ? -gy : (gy > 255 ? 510 - gy : gy);
        int gx = x0 + px - DIL; gx = gx < 0 ? -gx : (gx > 255 ? 510 - gx : gx);
        Xs[p * 72 + c] = in[bbase + (c << 16) + (gy << 8) + gx];
    }

    int wave = t >> 6, lane = t & 63;
    int l15 = lane & 15, quad = lane >> 4;
    f32x4 acc[4][4];
    #pragma unroll
    for (int i = 0; i < 4; i++)
        #pragma unroll
        for (int m = 0; m < 4; m++) acc[i][m] = (f32x4){0.f, 0.f, 0.f, 0.f};

    for (int tap = 0; tap < 9; tap++) {
        __syncthreads();
        const uint32* src = (const uint32*)(wt + tap * 4096);  // 2048 uints
        #pragma unroll
        for (int i = 0; i < 8; i++) {
            int idx = i * 256 + t;
            int o = idx >> 5, c2 = idx & 31;
            *(uint32*)&Ws[o * 72 + c2 * 2] = src[idx];
        }
        __syncthreads();
        int ky = tap / 3, kx = tap - ky * 3;
        #pragma unroll
        for (int kc = 0; kc < 2; kc++) {
            half8 af[4];
            #pragma unroll
            for (int m = 0; m < 4; m++)
                af[m] = *(const half8*)&Ws[(m * 16 + l15) * 72 + kc * 32 + quad * 8];
            #pragma unroll
            for (int i = 0; i < 4; i++) {
                int nt = wave * 4 + i;                 // 0..15
                int py = (nt >> 1) + ky * DIL;
                int px = (nt & 1) * 16 + l15 + kx * DIL;
                half8 bf = *(const half8*)&Xs[(py * PW + px) * 72 + kc * 32 + quad * 8];
                #pragma unroll
                for (int m = 0; m < 4; m++)
                    acc[i][m] = __builtin_amdgcn_mfma_f32_16x16x32_f16(af[m], bf, acc[i][m], 0, 0, 0);
            }
        }
    }

    #pragma unroll
    for (int i = 0; i < 4; i++) {
        int nt = wave * 4 + i;
        int hw = ((y0 + (nt >> 1)) << 8) + x0 + (nt & 1) * 16 + l15;
        #pragma unroll
        for (int m = 0; m < 4; m++) {
            #pragma unroll
            for (int r = 0; r < 4; r++) {
                int o = m * 16 + quad * 4 + r;
                float z = acc[i][m][r] + bias[o];
                z = z > 0.f ? z : 0.2f * z;
                int ga = bbase + (o << 16) + hw;
                if (res) z += ldval(res, ga);
                stval(out, ga, z);
            }
        }
    }
}

extern "C" void kernel_launch(void* const* d_in, const int* in_sizes, int n_in,
                              void* d_out, int out_size, void* d_ws, size_t ws_size,
                              hipStream_t stream) {
    const float* x   = (const float*)d_in[0];
    float*       scr = (float*)d_in[1];        // mask: unused by math -> scratch
    const float* wq  = (const float*)d_in[2];
    const float* bq  = (const float*)d_in[3];
    const float* wk  = (const float*)d_in[4];
    const float* bk  = (const float*)d_in[5];
    const float* wv  = (const float*)d_in[6];
    const float* bv  = (const float*)d_in[7];
    const float* wo  = (const float*)d_in[8];
    const float* bo  = (const float*)d_in[9];
    const float* wf1 = (const float*)d_in[10];
    const float* bf1 = (const float*)d_in[11];
    const float* wf2 = (const float*)d_in[12];
    const float* bf2 = (const float*)d_in[13];

    __half* wsA  = (__half*)d_ws;                        // q, then x1
    __half* wsB  = (__half*)((char*)d_ws + 67108864);    // k, then ff1
    __half* vbuf = (__half*)d_out;                       // v
    __half* ybuf = vbuf + 33554432;                      // y
    float*  outf = (float*)d_out;
    float*  sc   = scr;
    const __half* wh    = (const __half*)(scr + 262144);
    const __half* wqkv  = wh;                            // [192][64]
    const __half* wTo   = wh + 12288;                    // [9][64][64]
    const __half* wT1   = wh + 12288 + 36864;
    const __half* wT2   = wh + 12288 + 73728;

    prep_kernel<<<1504, 256, 0, stream>>>(wq, wk, wv, wo, wf1, wf2, scr);
    qkv_mfma<<<2048, 512, 0, stream>>>(x, wqkv, bq, bk, bv, wsA, wsB, vbuf);
    scores_kernel<<<dim3(8, 64), 256, 0, stream>>>(wsA, wsB, sc);
    softmax_kernel<<<4096, 64, 0, stream>>>(sc);
    attnout_kernel<<<dim3(8, 64), 256, 0, stream>>>(sc, vbuf, ybuf);
    // x1 = x + lrelu(conv_o(y))        -> wsA (fp16)
    conv3x3_mfma<1, float, __half><<<2048, 256, 0, stream>>>(ybuf, wTo, bo, x, wsA);
    // ff1 = lrelu(conv_f1(x1, dil=2))  -> wsB (fp16)
    conv3x3_mfma<2, float, __half><<<2048, 256, 0, stream>>>(wsA, wT1, bf1, (const float*)nullptr, wsB);
    // out = x1 + lrelu(conv_f2(ff1))   -> d_out (fp32)
    conv3x3_mfma<1, __half, float><<<2048, 256, 0, stream>>>(wsB, wT2, bf2, wsA, outf);
}